// Round 1
// baseline (355.557 us; speedup 1.0000x reference)
//
#include <hip/hip_runtime.h>
#include <math.h>

#define Bsz 16
#define Ssz 1024
#define TOKENS (Bsz * Ssz)   // 16384
#define Dd 64
#define Hh 8
#define NQd 8
#define FFNd 128
#define ACHUNKS 4

__device__ __forceinline__ float wave_reduce_sum(float v) {
#pragma unroll
  for (int off = 32; off >= 1; off >>= 1) v += __shfl_xor(v, off, 64);
  return v;
}

// ---------------------------------------------------------------- embed + pos
__global__ __launch_bounds__(256) void embed_kernel(
    const int* __restrict__ tokens, const float* __restrict__ emb,
    float* __restrict__ x) {
  int gid = blockIdx.x * 256 + threadIdx.x;   // 0 .. TOKENS*64-1
  if (gid >= TOKENS * Dd) return;
  int d  = gid & 63;
  int ts = gid >> 6;            // b*1024 + s
  int s  = ts & (Ssz - 1);
  int tok = tokens[ts];
  int k = d >> 1;
  // div_k = exp(2k * (-ln(10000)/64))
  float freq = expf((float)(2 * k) * (-0.14391156831f));
  float ang = (float)s * freq;
  float pe = (d & 1) ? cosf(ang) : sinf(ang);
  x[gid] = emb[(size_t)tok * Dd + d] + pe;
}

// ------------------------------------------------- quantum heads + attention
// grid.x = B*H*ACHUNKS, 256 threads. Each block: compute q for all 1024 keys
// of its (b,h) into LDS, then each thread owns one query row.
__global__ __launch_bounds__(256) void attn_kernel(
    const float* __restrict__ x, const float* __restrict__ theta,
    float* __restrict__ attn_out) {
  __shared__ float qs[Ssz][NQd];   // 32 KB
  int bh = blockIdx.x / ACHUNKS;
  int chunk = blockIdx.x % ACHUNKS;
  int b = bh >> 3, h = bh & 7;
  float th[8];
#pragma unroll
  for (int i = 0; i < 8; i++) th[i] = theta[i];

  const float* xb = x + ((size_t)b * Ssz) * Dd + h * NQd;
  for (int s = threadIdx.x; s < Ssz; s += 256) {
    const float* xp = xb + (size_t)s * Dd;
    float4 v0 = *(const float4*)(xp);
    float4 v1 = *(const float4*)(xp + 4);
    float c[8];
    c[0] = __cosf(v0.x + th[0]); c[1] = __cosf(v0.y + th[1]);
    c[2] = __cosf(v0.z + th[2]); c[3] = __cosf(v0.w + th[3]);
    c[4] = __cosf(v1.x + th[4]); c[5] = __cosf(v1.y + th[5]);
    c[6] = __cosf(v1.z + th[6]); c[7] = __cosf(v1.w + th[7]);
    float o[8];
    float cp = c[0];
#pragma unroll
    for (int j = 1; j < 8; j++) { cp *= c[j]; o[j] = cp; }
    float z0 = c[1];
#pragma unroll
    for (int j = 2; j < 8; j++) z0 *= c[j];
    o[0] = z0;
#pragma unroll
    for (int i = 0; i < 8; i++) qs[s][i] = o[i];
  }
  __syncthreads();

  int row = chunk * 256 + threadIdx.x;
  float qr[8];
#pragma unroll
  for (int i = 0; i < 8; i++) qr[i] = qs[row][i];
  float acc[8] = {0.f, 0.f, 0.f, 0.f, 0.f, 0.f, 0.f, 0.f};
  float psum = 0.f;
  const float scale = 0.35355339059327373f;  // 1/sqrt(8)
  // |score| <= 8/sqrt(8) = 2.83 -> exp never overflows; no running max needed.
#pragma unroll 4
  for (int k = 0; k < Ssz; k++) {
    float4 k0 = *(const float4*)&qs[k][0];
    float4 k1 = *(const float4*)&qs[k][4];
    float s = qr[0] * k0.x + qr[1] * k0.y + qr[2] * k0.z + qr[3] * k0.w +
              qr[4] * k1.x + qr[5] * k1.y + qr[6] * k1.z + qr[7] * k1.w;
    float e = __expf(s * scale);
    psum += e;
    acc[0] += e * k0.x; acc[1] += e * k0.y;
    acc[2] += e * k0.z; acc[3] += e * k0.w;
    acc[4] += e * k1.x; acc[5] += e * k1.y;
    acc[6] += e * k1.z; acc[7] += e * k1.w;
  }
  float inv = 1.0f / psum;
  float* op = attn_out + ((size_t)(b * Ssz + row)) * Dd + h * NQd;
  float4 r0 = make_float4(acc[0] * inv, acc[1] * inv, acc[2] * inv, acc[3] * inv);
  float4 r1 = make_float4(acc[4] * inv, acc[5] * inv, acc[6] * inv, acc[7] * inv);
  *(float4*)(op) = r0;
  *(float4*)(op + 4) = r1;
}

// ---------------------- combine-matvec + residual + LN1 + FFN + residual + LN2
// One wave (64 lanes) per token; block = 4 waves, 64 tokens per block.
__global__ __launch_bounds__(256) void tail_kernel(
    float* __restrict__ x, const float* __restrict__ attn,
    const float* __restrict__ Wc,                        // [64][64]
    const float* __restrict__ g1, const float* __restrict__ bb1,
    const float* __restrict__ g2, const float* __restrict__ bb2,
    const float* __restrict__ fth,                       // [8]
    const float* __restrict__ W1, const float* __restrict__ fb1,  // [128][8],[128]
    const float* __restrict__ W2, const float* __restrict__ fb2,  // [64][128],[64]
    float* __restrict__ partial, int do_partial) {
  __shared__ float WcT[64][64];    // WcT[k][d] = Wc[d][k]   (16 KB)
  __shared__ float W2T[128][64];   // W2T[j][d] = W2[d][j]   (32 KB)
  __shared__ float a_s[4][64];
  __shared__ float h_s[4][128];
  __shared__ float red[4][64];
  int tid = threadIdx.x;
  int w = tid >> 6, lane = tid & 63;

  for (int i = tid; i < 64 * 64; i += 256) {
    int d = i >> 6, k = i & 63;
    WcT[k][d] = Wc[i];
  }
  for (int i = tid; i < 64 * 128; i += 256) {
    int d = i >> 7, j = i & 127;
    W2T[j][d] = W2[i];
  }
  float w1a[8], w1b[8];
#pragma unroll
  for (int i = 0; i < 8; i++) {
    w1a[i] = W1[lane * 8 + i];
    w1b[i] = W1[(lane + 64) * 8 + i];
  }
  float fb1a = fb1[lane], fb1b = fb1[lane + 64];
  float g1d = g1[lane], b1d = bb1[lane];
  float g2d = g2[lane], b2d = bb2[lane];
  float fb2d = fb2[lane];
  float cth[8];
#pragma unroll
  for (int i = 0; i < 8; i++) cth[i] = __cosf(fth[i]);
  __syncthreads();

  float pool = 0.f;
  int tok0 = blockIdx.x * 64;
  for (int it = 0; it < 16; ++it) {
    int tok = tok0 + w * 16 + it;
    size_t base = (size_t)tok * Dd + lane;
    float xd = x[base];
    float ad = attn[base];
    a_s[w][lane] = ad;
    __syncthreads();
    float y = 0.f;
#pragma unroll 8
    for (int k = 0; k < 64; k++) y += a_s[w][k] * WcT[k][lane];
    float r = xd + y;
    float mu = wave_reduce_sum(r) * (1.f / 64.f);
    float t = r - mu;
    float var = wave_reduce_sum(t * t) * (1.f / 64.f);
    float x1 = t * rsqrtf(var + 1e-5f) * g1d + b1d;
    // quantum FFN: z_i = cos(x1_i)*cos(theta_i), first 8 features
    float z[8];
#pragma unroll
    for (int i = 0; i < 8; i++) z[i] = __cosf(__shfl(x1, i, 64)) * cth[i];
    float ha = fb1a, hb = fb1b;
#pragma unroll
    for (int i = 0; i < 8; i++) { ha += z[i] * w1a[i]; hb += z[i] * w1b[i]; }
    ha = fmaxf(ha, 0.f); hb = fmaxf(hb, 0.f);
    h_s[w][lane] = ha;
    h_s[w][lane + 64] = hb;
    __syncthreads();
    float f = fb2d;
#pragma unroll 8
    for (int j = 0; j < 128; j++) f += h_s[w][j] * W2T[j][lane];
    float r2 = x1 + f;
    float mu2 = wave_reduce_sum(r2) * (1.f / 64.f);
    float t2 = r2 - mu2;
    float var2 = wave_reduce_sum(t2 * t2) * (1.f / 64.f);
    float xo = t2 * rsqrtf(var2 + 1e-5f) * g2d + b2d;
    x[base] = xo;
    pool += xo;
    __syncthreads();
  }
  if (do_partial) {
    red[w][lane] = pool;
    __syncthreads();
    if (w == 0) {
      float s = red[0][lane] + red[1][lane] + red[2][lane] + red[3][lane];
      partial[(size_t)blockIdx.x * 64 + lane] = s;
    }
  }
}

// ------------------------------------------------ pooled mean + MLP head
__global__ __launch_bounds__(256) void head_kernel(
    const float* __restrict__ partial,   // [256][64]
    const float* eW1, const float* eb1, const float* eW2, const float* eb2,
    const float* eW3, const float* eb3, const float* dW1, const float* db1v,
    const float* dW2, const float* db2v, const float* dW3, const float* db3v,
    const float* cW, const float* cb, float* __restrict__ out) {
  __shared__ float bufA[16][128];
  __shared__ float bufB[16][128];
  int tid = threadIdx.x;
  // pooled -> bufA[b][0..63]
  for (int o = tid; o < 16 * 64; o += 256) {
    int b = o >> 6, d = o & 63;
    float s = 0.f;
    for (int c = 0; c < 16; ++c) s += partial[(size_t)(b * 16 + c) * 64 + d];
    bufA[b][d] = s * (1.f / 1024.f);
  }
  __syncthreads();
  // enc1: 64 -> 128, relu
  for (int o = tid; o < 16 * 128; o += 256) {
    int b = o >> 7, i = o & 127;
    float v = eb1[i];
    for (int d = 0; d < 64; d++) v += bufA[b][d] * eW1[i * 64 + d];
    bufB[b][i] = fmaxf(v, 0.f);
  }
  __syncthreads();
  // enc2: 128 -> 64, relu
  for (int o = tid; o < 16 * 64; o += 256) {
    int b = o >> 6, i = o & 63;
    float v = eb2[i];
    for (int j = 0; j < 128; j++) v += bufB[b][j] * eW2[i * 128 + j];
    bufA[b][i] = fmaxf(v, 0.f);
  }
  __syncthreads();
  // enc3: 64 -> 32 (no relu)
  for (int o = tid; o < 16 * 32; o += 256) {
    int b = o >> 5, i = o & 31;
    float v = eb3[i];
    for (int d = 0; d < 64; d++) v += bufA[b][d] * eW3[i * 64 + d];
    bufB[b][i] = v;
  }
  __syncthreads();
  // dec1: 32 -> 64, relu
  for (int o = tid; o < 16 * 64; o += 256) {
    int b = o >> 6, i = o & 63;
    float v = db1v[i];
    for (int k = 0; k < 32; k++) v += bufB[b][k] * dW1[i * 32 + k];
    bufA[b][i] = fmaxf(v, 0.f);
  }
  __syncthreads();
  // dec2: 64 -> 128, relu
  for (int o = tid; o < 16 * 128; o += 256) {
    int b = o >> 7, i = o & 127;
    float v = db2v[i];
    for (int k = 0; k < 64; k++) v += bufA[b][k] * dW2[i * 64 + k];
    bufB[b][i] = fmaxf(v, 0.f);
  }
  __syncthreads();
  // dec3: 128 -> 64 (no relu)
  for (int o = tid; o < 16 * 64; o += 256) {
    int b = o >> 6, i = o & 63;
    float v = db3v[i];
    for (int j = 0; j < 128; j++) v += bufB[b][j] * dW3[i * 128 + j];
    bufA[b][i] = v;
  }
  __syncthreads();
  // classifier: 64 -> 10
  for (int o = tid; o < 16 * 10; o += 256) {
    int b = o / 10, c = o % 10;
    float v = cb[c];
    for (int d = 0; d < 64; d++) v += bufA[b][d] * cW[c * 64 + d];
    out[o] = v;
  }
}

extern "C" void kernel_launch(void* const* d_in, const int* in_sizes, int n_in,
                              void* d_out, int out_size, void* d_ws, size_t ws_size,
                              hipStream_t stream) {
  const int*   tokens     = (const int*)d_in[0];
  const float* emb        = (const float*)d_in[1];
  const float* attn_theta = (const float*)d_in[2];
  const float* combine_W  = (const float*)d_in[3];
  const float* ln1_g      = (const float*)d_in[4];
  const float* ln1_b      = (const float*)d_in[5];
  const float* ln2_g      = (const float*)d_in[6];
  const float* ln2_b      = (const float*)d_in[7];
  const float* ffn_theta  = (const float*)d_in[8];
  const float* ffn_W1     = (const float*)d_in[9];
  const float* ffn_b1     = (const float*)d_in[10];
  const float* ffn_W2     = (const float*)d_in[11];
  const float* ffn_b2     = (const float*)d_in[12];
  const float* enc_W1 = (const float*)d_in[13]; const float* enc_b1 = (const float*)d_in[14];
  const float* enc_W2 = (const float*)d_in[15]; const float* enc_b2 = (const float*)d_in[16];
  const float* enc_W3 = (const float*)d_in[17]; const float* enc_b3 = (const float*)d_in[18];
  const float* dec_W1 = (const float*)d_in[19]; const float* dec_b1 = (const float*)d_in[20];
  const float* dec_W2 = (const float*)d_in[21]; const float* dec_b2 = (const float*)d_in[22];
  const float* dec_W3 = (const float*)d_in[23]; const float* dec_b3 = (const float*)d_in[24];
  const float* cls_W  = (const float*)d_in[25]; const float* cls_b  = (const float*)d_in[26];

  float* x        = (float*)d_ws;              // TOKENS*64 floats (4 MB)
  float* attn_out = x + (size_t)TOKENS * 64;   // TOKENS*64 floats (4 MB)
  float* partial  = attn_out + (size_t)TOKENS * 64;  // 256*64 floats
  float* out      = (float*)d_out;

  embed_kernel<<<(TOKENS * Dd + 255) / 256, 256, 0, stream>>>(tokens, emb, x);
  for (int l = 0; l < 2; ++l) {
    attn_kernel<<<Bsz * Hh * ACHUNKS, 256, 0, stream>>>(
        x, attn_theta + l * 8, attn_out);
    tail_kernel<<<TOKENS / 64, 256, 0, stream>>>(
        x, attn_out, combine_W + l * 4096,
        ln1_g + l * 64, ln1_b + l * 64, ln2_g + l * 64, ln2_b + l * 64,
        ffn_theta + l * 8, ffn_W1 + l * 1024, ffn_b1 + l * 128,
        ffn_W2 + l * 8192, ffn_b2 + l * 64, partial, (l == 1) ? 1 : 0);
  }
  head_kernel<<<1, 256, 0, stream>>>(partial, enc_W1, enc_b1, enc_W2, enc_b2,
                                     enc_W3, enc_b3, dec_W1, dec_b1, dec_W2,
                                     dec_b2, dec_W3, dec_b3, cls_W, cls_b, out);
}

// Round 2
// 293.414 us; speedup vs baseline: 1.2118x; 1.2118x over previous
//
#include <hip/hip_runtime.h>
#include <math.h>

typedef float f32x2 __attribute__((ext_vector_type(2)));

#define Bsz 16
#define Ssz 1024
#define TOKENS (Bsz * Ssz)   // 16384
#define Dd 64
#define Hh 8
#define KSPLIT 4
#define KCH (Ssz / KSPLIT)   // 256 keys per attn block

#if __has_builtin(__builtin_amdgcn_exp2f)
  #define EXPFN(x) __builtin_amdgcn_exp2f(x)
  #define PRESCALE 0.51007025f          // (1/sqrt(8)) * log2(e)
#else
  #define EXPFN(x) __expf(x)
  #define PRESCALE 0.35355339059f       // 1/sqrt(8)
#endif

__device__ __forceinline__ float wave_reduce_sum(float v) {
#pragma unroll
  for (int off = 32; off >= 1; off >>= 1) v += __shfl_xor(v, off, 64);
  return v;
}

// quantum head q-vector for one token/head: o[8]
__device__ __forceinline__ void qheads(const float* __restrict__ xp,
                                       const float* th, float* o) {
  float4 v0 = *(const float4*)(xp);
  float4 v1 = *(const float4*)(xp + 4);
  float c0 = __cosf(v0.x + th[0]), c1 = __cosf(v0.y + th[1]);
  float c2 = __cosf(v0.z + th[2]), c3 = __cosf(v0.w + th[3]);
  float c4 = __cosf(v1.x + th[4]), c5 = __cosf(v1.y + th[5]);
  float c6 = __cosf(v1.z + th[6]), c7 = __cosf(v1.w + th[7]);
  float cp = c0;
  cp *= c1; o[1] = cp; cp *= c2; o[2] = cp; cp *= c3; o[3] = cp;
  cp *= c4; o[4] = cp; cp *= c5; o[5] = cp; cp *= c6; o[6] = cp;
  cp *= c7; o[7] = cp;
  o[0] = c1 * c2 * c3 * c4 * c5 * c6 * c7;
}

// ---------------------------------------------------------------- embed + pos
__global__ __launch_bounds__(256) void embed_kernel(
    const int* __restrict__ tokens, const float* __restrict__ emb,
    float* __restrict__ x) {
  int gid = blockIdx.x * 256 + threadIdx.x;
  if (gid >= TOKENS * Dd) return;
  int d  = gid & 63;
  int ts = gid >> 6;
  int s  = ts & (Ssz - 1);
  int tok = tokens[ts];
  int k = d >> 1;
  float freq = expf((float)(2 * k) * (-0.14391156831f));
  float ang = (float)s * freq;
  float pe = (d & 1) ? cosf(ang) : sinf(ang);
  x[gid] = emb[(size_t)tok * Dd + d] + pe;
}

// ------------------------------------------------- quantum heads + attention
// grid = 128 bh * 2 rowchunks * 4 ksplit = 1024 blocks, 256 threads.
// Each thread: 2 rows x KCH keys -> partial (acc[8], psum) per ksplit.
__global__ __launch_bounds__(256, 4) void attn_kernel(
    const float* __restrict__ x, const float* __restrict__ theta,
    float* __restrict__ apart) {
  __shared__ float qs[KCH][8];   // 8 KB
  int blk = blockIdx.x;
  int bh  = blk >> 3;
  int sub = blk & 7;
  int rc  = sub >> 2;            // row chunk 0/1
  int ks  = sub & 3;             // key split 0..3
  int b = bh >> 3, h = bh & 7;
  int t = threadIdx.x;

  float th[8];
#pragma unroll
  for (int i = 0; i < 8; i++) th[i] = theta[i];

  const float* xb = x + (size_t)b * Ssz * Dd + h * 8;

  // stage this block's keys
  {
    int k = ks * KCH + t;
    float o[8];
    qheads(xb + (size_t)k * Dd, th, o);
#pragma unroll
    for (int i = 0; i < 8; i++) qs[t][i] = o[i];
  }

  // this thread's two rows
  int r0 = rc * 512 + t;
  int r1 = r0 + 256;
  float q0[8], q1[8];
  qheads(xb + (size_t)r0 * Dd, th, q0);
  qheads(xb + (size_t)r1 * Dd, th, q1);
  f32x2 qp0[4], qp1[4];
#pragma unroll
  for (int j = 0; j < 4; j++) {
    qp0[j] = (f32x2){q0[2 * j] * PRESCALE, q0[2 * j + 1] * PRESCALE};
    qp1[j] = (f32x2){q1[2 * j] * PRESCALE, q1[2 * j + 1] * PRESCALE};
  }
  __syncthreads();

  f32x2 a0[4], a1[4];
#pragma unroll
  for (int j = 0; j < 4; j++) { a0[j] = (f32x2){0.f, 0.f}; a1[j] = (f32x2){0.f, 0.f}; }
  float ps0 = 0.f, ps1 = 0.f;

#pragma unroll 2
  for (int k = 0; k < KCH; ++k) {
    float4 ka = *(const float4*)&qs[k][0];
    float4 kb = *(const float4*)&qs[k][4];
    f32x2 k0 = (f32x2){ka.x, ka.y};
    f32x2 k1 = (f32x2){ka.z, ka.w};
    f32x2 k2 = (f32x2){kb.x, kb.y};
    f32x2 k3 = (f32x2){kb.z, kb.w};

    f32x2 d0 = k0 * qp0[0];
    d0 = __builtin_elementwise_fma(k1, qp0[1], d0);
    d0 = __builtin_elementwise_fma(k2, qp0[2], d0);
    d0 = __builtin_elementwise_fma(k3, qp0[3], d0);
    f32x2 d1 = k0 * qp1[0];
    d1 = __builtin_elementwise_fma(k1, qp1[1], d1);
    d1 = __builtin_elementwise_fma(k2, qp1[2], d1);
    d1 = __builtin_elementwise_fma(k3, qp1[3], d1);

    float e0 = EXPFN(d0.x + d0.y);
    float e1 = EXPFN(d1.x + d1.y);
    ps0 += e0; ps1 += e1;
    f32x2 ev0 = (f32x2){e0, e0};
    f32x2 ev1 = (f32x2){e1, e1};
    a0[0] = __builtin_elementwise_fma(k0, ev0, a0[0]);
    a0[1] = __builtin_elementwise_fma(k1, ev0, a0[1]);
    a0[2] = __builtin_elementwise_fma(k2, ev0, a0[2]);
    a0[3] = __builtin_elementwise_fma(k3, ev0, a0[3]);
    a1[0] = __builtin_elementwise_fma(k0, ev1, a1[0]);
    a1[1] = __builtin_elementwise_fma(k1, ev1, a1[1]);
    a1[2] = __builtin_elementwise_fma(k2, ev1, a1[2]);
    a1[3] = __builtin_elementwise_fma(k3, ev1, a1[3]);
  }

  // partial layout: apart[(bh*4+ks)*9*1024 + c*1024 + row], c=0..7 acc, c=8 psum
  size_t base = ((size_t)(bh * KSPLIT + ks)) * 9 * 1024;
#pragma unroll
  for (int j = 0; j < 4; j++) {
    apart[base + (2 * j) * 1024 + r0]     = a0[j].x;
    apart[base + (2 * j + 1) * 1024 + r0] = a0[j].y;
    apart[base + (2 * j) * 1024 + r1]     = a1[j].x;
    apart[base + (2 * j + 1) * 1024 + r1] = a1[j].y;
  }
  apart[base + 8 * 1024 + r0] = ps0;
  apart[base + 8 * 1024 + r1] = ps1;
}

// sum ksplit partials, normalize, write attn_out[b,s,64]
__global__ __launch_bounds__(256) void attn_combine(
    const float* __restrict__ apart, float* __restrict__ attn_out) {
  int gid = blockIdx.x * 256 + threadIdx.x;   // 131072 = 128bh * 1024rows
  int bh = gid >> 10, row = gid & 1023;
  int b = bh >> 3, h = bh & 7;
  float v[9];
#pragma unroll
  for (int c = 0; c < 9; c++) v[c] = 0.f;
  for (int ks = 0; ks < KSPLIT; ks++) {
    size_t base = ((size_t)(bh * KSPLIT + ks)) * 9 * 1024 + row;
#pragma unroll
    for (int c = 0; c < 9; c++) v[c] += apart[base + c * 1024];
  }
  float inv = 1.0f / v[8];
  float* op = attn_out + ((size_t)(b * Ssz + row)) * Dd + h * 8;
  *(float4*)op       = make_float4(v[0] * inv, v[1] * inv, v[2] * inv, v[3] * inv);
  *(float4*)(op + 4) = make_float4(v[4] * inv, v[5] * inv, v[6] * inv, v[7] * inv);
}

// ---------------------- combine-matvec + LN1 + FFN + LN2, 16 tokens per block
__global__ __launch_bounds__(256) void tail_kernel(
    float* __restrict__ x, const float* __restrict__ attn,
    const float* __restrict__ Wc,
    const float* __restrict__ g1, const float* __restrict__ bb1,
    const float* __restrict__ g2, const float* __restrict__ bb2,
    const float* __restrict__ fth,
    const float* __restrict__ W1, const float* __restrict__ fb1,
    const float* __restrict__ W2, const float* __restrict__ fb2,
    float* __restrict__ partial, int do_partial) {
  __shared__ float WcS[64 * 64];    // [k][d xor-swizzled]
  __shared__ float W2S[128 * 64];   // [j][d xor-swizzled]
  __shared__ float a_s[4][64];
  __shared__ float h_s[4][128];
  __shared__ float red[4][64];
  int tid = threadIdx.x;
  int w = tid >> 6, lane = tid & 63;

  for (int i = tid; i < 64 * 64; i += 256) {
    int d = i >> 6, k = i & 63;
    WcS[k * 64 + (d ^ (k & 31))] = Wc[i];     // conflict-free store & load
  }
  for (int i = tid; i < 64 * 128; i += 256) {
    int d = i >> 7, j = i & 127;
    W2S[j * 64 + (d ^ (j & 31))] = W2[i];
  }
  float w1a[8], w1b[8];
#pragma unroll
  for (int i = 0; i < 8; i++) {
    w1a[i] = W1[lane * 8 + i];
    w1b[i] = W1[(lane + 64) * 8 + i];
  }
  float fb1a = fb1[lane], fb1b = fb1[lane + 64];
  float g1d = g1[lane], b1d = bb1[lane];
  float g2d = g2[lane], b2d = bb2[lane];
  float fb2d = fb2[lane];
  float cth[8];
#pragma unroll
  for (int i = 0; i < 8; i++) cth[i] = __cosf(fth[i]);
  __syncthreads();

  float pool = 0.f;
  int tok0 = blockIdx.x * 16;
  for (int it = 0; it < 4; ++it) {
    int tok = tok0 + w * 4 + it;
    size_t base = (size_t)tok * Dd + lane;
    float xd = x[base];
    float ad = attn[base];
    a_s[w][lane] = ad;                 // wave-private: no barrier needed
    float y0 = 0.f, y1 = 0.f, y2 = 0.f, y3 = 0.f;
#pragma unroll
    for (int k4 = 0; k4 < 16; k4++) {
      float4 av = *(const float4*)&a_s[w][k4 * 4];
      int k = k4 * 4;
      y0 = fmaf(av.x, WcS[(k + 0) * 64 + (lane ^ ((k + 0) & 31))], y0);
      y1 = fmaf(av.y, WcS[(k + 1) * 64 + (lane ^ ((k + 1) & 31))], y1);
      y2 = fmaf(av.z, WcS[(k + 2) * 64 + (lane ^ ((k + 2) & 31))], y2);
      y3 = fmaf(av.w, WcS[(k + 3) * 64 + (lane ^ ((k + 3) & 31))], y3);
    }
    float r = xd + ((y0 + y1) + (y2 + y3));
    float mu = wave_reduce_sum(r) * (1.f / 64.f);
    float tt = r - mu;
    float var = wave_reduce_sum(tt * tt) * (1.f / 64.f);
    float x1 = tt * rsqrtf(var + 1e-5f) * g1d + b1d;
    float z[8];
#pragma unroll
    for (int i = 0; i < 8; i++) z[i] = __cosf(__shfl(x1, i, 64)) * cth[i];
    float ha = fb1a, hb = fb1b;
#pragma unroll
    for (int i = 0; i < 8; i++) { ha += z[i] * w1a[i]; hb += z[i] * w1b[i]; }
    ha = fmaxf(ha, 0.f); hb = fmaxf(hb, 0.f);
    h_s[w][lane] = ha;
    h_s[w][lane + 64] = hb;
    float f0 = 0.f, f1 = 0.f, f2 = 0.f, f3 = 0.f;
#pragma unroll
    for (int j4 = 0; j4 < 32; j4++) {
      float4 hv = *(const float4*)&h_s[w][j4 * 4];
      int j = j4 * 4;
      f0 = fmaf(hv.x, W2S[(j + 0) * 64 + (lane ^ ((j + 0) & 31))], f0);
      f1 = fmaf(hv.y, W2S[(j + 1) * 64 + (lane ^ ((j + 1) & 31))], f1);
      f2 = fmaf(hv.z, W2S[(j + 2) * 64 + (lane ^ ((j + 2) & 31))], f2);
      f3 = fmaf(hv.w, W2S[(j + 3) * 64 + (lane ^ ((j + 3) & 31))], f3);
    }
    float f = fb2d + ((f0 + f1) + (f2 + f3));
    float r2 = x1 + f;
    float mu2 = wave_reduce_sum(r2) * (1.f / 64.f);
    float t2 = r2 - mu2;
    float var2 = wave_reduce_sum(t2 * t2) * (1.f / 64.f);
    float xo = t2 * rsqrtf(var2 + 1e-5f) * g2d + b2d;
    x[base] = xo;
    pool += xo;
  }
  if (do_partial) {
    red[w][lane] = pool;
    __syncthreads();
    if (w == 0) {
      float s = red[0][lane] + red[1][lane] + red[2][lane] + red[3][lane];
      partial[(size_t)blockIdx.x * 64 + lane] = s;
    }
  }
}

// ------------------------------------------------ pooled mean + MLP head
__global__ __launch_bounds__(256) void head_kernel(
    const float* __restrict__ partial,   // [1024][64]
    const float* eW1, const float* eb1, const float* eW2, const float* eb2,
    const float* eW3, const float* eb3, const float* dW1, const float* db1v,
    const float* dW2, const float* db2v, const float* dW3, const float* db3v,
    const float* cW, const float* cb, float* __restrict__ out) {
  __shared__ float bufA[16][128];
  __shared__ float bufB[16][128];
  int tid = threadIdx.x;
  for (int o = tid; o < 16 * 64; o += 256) {
    int b = o >> 6, d = o & 63;
    float s = 0.f;
    for (int c = 0; c < 64; ++c) s += partial[(size_t)(b * 64 + c) * 64 + d];
    bufA[b][d] = s * (1.f / 1024.f);
  }
  __syncthreads();
  for (int o = tid; o < 16 * 128; o += 256) {
    int b = o >> 7, i = o & 127;
    float v = eb1[i];
    for (int d = 0; d < 64; d++) v += bufA[b][d] * eW1[i * 64 + d];
    bufB[b][i] = fmaxf(v, 0.f);
  }
  __syncthreads();
  for (int o = tid; o < 16 * 64; o += 256) {
    int b = o >> 6, i = o & 63;
    float v = eb2[i];
    for (int j = 0; j < 128; j++) v += bufB[b][j] * eW2[i * 128 + j];
    bufA[b][i] = fmaxf(v, 0.f);
  }
  __syncthreads();
  for (int o = tid; o < 16 * 32; o += 256) {
    int b = o >> 5, i = o & 31;
    float v = eb3[i];
    for (int d = 0; d < 64; d++) v += bufA[b][d] * eW3[i * 64 + d];
    bufB[b][i] = v;
  }
  __syncthreads();
  for (int o = tid; o < 16 * 64; o += 256) {
    int b = o >> 6, i = o & 63;
    float v = db1v[i];
    for (int k = 0; k < 32; k++) v += bufB[b][k] * dW1[i * 32 + k];
    bufA[b][i] = fmaxf(v, 0.f);
  }
  __syncthreads();
  for (int o = tid; o < 16 * 128; o += 256) {
    int b = o >> 7, i = o & 127;
    float v = db2v[i];
    for (int k = 0; k < 64; k++) v += bufA[b][k] * dW2[i * 64 + k];
    bufB[b][i] = fmaxf(v, 0.f);
  }
  __syncthreads();
  for (int o = tid; o < 16 * 64; o += 256) {
    int b = o >> 6, i = o & 63;
    float v = db3v[i];
    for (int j = 0; j < 128; j++) v += bufB[b][j] * dW3[i * 128 + j];
    bufA[b][i] = v;
  }
  __syncthreads();
  for (int o = tid; o < 16 * 10; o += 256) {
    int b = o / 10, c = o % 10;
    float v = cb[c];
    for (int d = 0; d < 64; d++) v += bufA[b][d] * cW[c * 64 + d];
    out[o] = v;
  }
}

extern "C" void kernel_launch(void* const* d_in, const int* in_sizes, int n_in,
                              void* d_out, int out_size, void* d_ws, size_t ws_size,
                              hipStream_t stream) {
  const int*   tokens     = (const int*)d_in[0];
  const float* emb        = (const float*)d_in[1];
  const float* attn_theta = (const float*)d_in[2];
  const float* combine_W  = (const float*)d_in[3];
  const float* ln1_g      = (const float*)d_in[4];
  const float* ln1_b      = (const float*)d_in[5];
  const float* ln2_g      = (const float*)d_in[6];
  const float* ln2_b      = (const float*)d_in[7];
  const float* ffn_theta  = (const float*)d_in[8];
  const float* ffn_W1     = (const float*)d_in[9];
  const float* ffn_b1     = (const float*)d_in[10];
  const float* ffn_W2     = (const float*)d_in[11];
  const float* ffn_b2     = (const float*)d_in[12];
  const float* enc_W1 = (const float*)d_in[13]; const float* enc_b1 = (const float*)d_in[14];
  const float* enc_W2 = (const float*)d_in[15]; const float* enc_b2 = (const float*)d_in[16];
  const float* enc_W3 = (const float*)d_in[17]; const float* enc_b3 = (const float*)d_in[18];
  const float* dec_W1 = (const float*)d_in[19]; const float* dec_b1 = (const float*)d_in[20];
  const float* dec_W2 = (const float*)d_in[21]; const float* dec_b2 = (const float*)d_in[22];
  const float* dec_W3 = (const float*)d_in[23]; const float* dec_b3 = (const float*)d_in[24];
  const float* cls_W  = (const float*)d_in[25]; const float* cls_b  = (const float*)d_in[26];

  float* x        = (float*)d_ws;                          // 1M floats
  float* attn_out = x + (size_t)TOKENS * 64;               // 1M floats
  float* apart    = attn_out + (size_t)TOKENS * 64;        // 512*9*1024 = 4.72M floats
  float* partial  = apart + (size_t)128 * KSPLIT * 9 * 1024;  // 1024*64 floats
  float* out      = (float*)d_out;

  embed_kernel<<<(TOKENS * Dd + 255) / 256, 256, 0, stream>>>(tokens, emb, x);
  for (int l = 0; l < 2; ++l) {
    attn_kernel<<<128 * 2 * KSPLIT, 256, 0, stream>>>(x, attn_theta + l * 8, apart);
    attn_combine<<<128 * 1024 / 256, 256, 0, stream>>>(apart, attn_out);
    tail_kernel<<<TOKENS / 16, 256, 0, stream>>>(
        x, attn_out, combine_W + l * 4096,
        ln1_g + l * 64, ln1_b + l * 64, ln2_g + l * 64, ln2_b + l * 64,
        ffn_theta + l * 8, ffn_W1 + l * 1024, ffn_b1 + l * 128,
        ffn_W2 + l * 8192, ffn_b2 + l * 64, partial, (l == 1) ? 1 : 0);
  }
  head_kernel<<<1, 256, 0, stream>>>(partial, enc_W1, enc_b1, enc_W2, enc_b2,
                                     enc_W3, enc_b3, dec_W1, dec_b1, dec_W2,
                                     dec_b2, dec_W3, dec_b3, cls_W, cls_b, out);
}

// Round 3
// 223.400 us; speedup vs baseline: 1.5916x; 1.3134x over previous
//
#include <hip/hip_runtime.h>
#include <math.h>

typedef float f32x2 __attribute__((ext_vector_type(2)));

#define Bsz 16
#define Ssz 1024
#define TOKENS (Bsz * Ssz)   // 16384
#define Dd 64
#define Hh 8
#define KSPLIT 4
#define KCH (Ssz / KSPLIT)   // 256 keys per attn block

#if __has_builtin(__builtin_amdgcn_exp2f)
  #define EXPFN(x) __builtin_amdgcn_exp2f(x)
  #define PRESCALE 0.51007025f          // (1/sqrt(8)) * log2(e)
#else
  #define EXPFN(x) __expf(x)
  #define PRESCALE 0.35355339059f       // 1/sqrt(8)
#endif

__device__ __forceinline__ f32x2 pk_fma(f32x2 a, f32x2 b, f32x2 c) {
  f32x2 d;
  asm("v_pk_fma_f32 %0, %1, %2, %3" : "=v"(d) : "v"(a), "v"(b), "v"(c));
  return d;
}
__device__ __forceinline__ f32x2 pk_mul(f32x2 a, f32x2 b) {
  f32x2 d;
  asm("v_pk_mul_f32 %0, %1, %2" : "=v"(d) : "v"(a), "v"(b));
  return d;
}

#if __has_builtin(__builtin_amdgcn_readlane)
__device__ __forceinline__ float rdlane(float v, int l) {
  return __int_as_float(__builtin_amdgcn_readlane(__float_as_int(v), l));
}
#else
__device__ __forceinline__ float rdlane(float v, int l) { return __shfl(v, l, 64); }
#endif

__device__ __forceinline__ float wave_reduce_sum(float v) {
#pragma unroll
  for (int off = 32; off >= 1; off >>= 1) v += __shfl_xor(v, off, 64);
  return v;
}

// quantum head q-vector for one token/head
__device__ __forceinline__ void qheads(const float* __restrict__ xp,
                                       const float* th, float* o) {
  float4 v0 = *(const float4*)(xp);
  float4 v1 = *(const float4*)(xp + 4);
  float c0 = __cosf(v0.x + th[0]), c1 = __cosf(v0.y + th[1]);
  float c2 = __cosf(v0.z + th[2]), c3 = __cosf(v0.w + th[3]);
  float c4 = __cosf(v1.x + th[4]), c5 = __cosf(v1.y + th[5]);
  float c6 = __cosf(v1.z + th[6]), c7 = __cosf(v1.w + th[7]);
  float cp = c0;
  cp *= c1; o[1] = cp; cp *= c2; o[2] = cp; cp *= c3; o[3] = cp;
  cp *= c4; o[4] = cp; cp *= c5; o[5] = cp; cp *= c6; o[6] = cp;
  cp *= c7; o[7] = cp;
  o[0] = c1 * c2 * c3 * c4 * c5 * c6 * c7;
}

// ---------------------------------------------------------------- embed + pos
__global__ __launch_bounds__(256) void embed_kernel(
    const int* __restrict__ tokens, const float* __restrict__ emb,
    float* __restrict__ x) {
  int gid = blockIdx.x * 256 + threadIdx.x;
  if (gid >= TOKENS * Dd) return;
  int d  = gid & 63;
  int ts = gid >> 6;
  int s  = ts & (Ssz - 1);
  int tok = tokens[ts];
  int k = d >> 1;
  float freq = expf((float)(2 * k) * (-0.14391156831f));
  float ang = (float)s * freq;
  float pe = (d & 1) ? cosf(ang) : sinf(ang);
  x[gid] = emb[(size_t)tok * Dd + d] + pe;
}

// ------------------------------------------------- quantum heads + attention
// grid = 128 bh * 2 rowchunks * 4 ksplit = 1024 blocks, 256 threads.
__global__ __launch_bounds__(256, 4) void attn_kernel(
    const float* __restrict__ x, const float* __restrict__ theta,
    float* __restrict__ apart) {
  __shared__ float qs[KCH][8];   // 8 KB
  int blk = blockIdx.x;
  int bh  = blk >> 3;
  int sub = blk & 7;
  int rc  = sub >> 2;
  int ks  = sub & 3;
  int b = bh >> 3, h = bh & 7;
  int t = threadIdx.x;

  float th[8];
#pragma unroll
  for (int i = 0; i < 8; i++) th[i] = theta[i];

  const float* xb = x + (size_t)b * Ssz * Dd + h * 8;

  {
    int k = ks * KCH + t;
    float o[8];
    qheads(xb + (size_t)k * Dd, th, o);
#pragma unroll
    for (int i = 0; i < 8; i++) qs[t][i] = o[i];
  }

  int r0 = rc * 512 + t;
  int r1 = r0 + 256;
  float q0[8], q1[8];
  qheads(xb + (size_t)r0 * Dd, th, q0);
  qheads(xb + (size_t)r1 * Dd, th, q1);
  f32x2 qp0[4], qp1[4];
#pragma unroll
  for (int j = 0; j < 4; j++) {
    qp0[j] = (f32x2){q0[2 * j] * PRESCALE, q0[2 * j + 1] * PRESCALE};
    qp1[j] = (f32x2){q1[2 * j] * PRESCALE, q1[2 * j + 1] * PRESCALE};
  }
  __syncthreads();

  f32x2 a0[4], a1[4];
#pragma unroll
  for (int j = 0; j < 4; j++) { a0[j] = (f32x2){0.f, 0.f}; a1[j] = (f32x2){0.f, 0.f}; }
  float ps0 = 0.f, ps1 = 0.f;

#pragma unroll 4
  for (int k = 0; k < KCH; ++k) {
    float4 ka = *(const float4*)&qs[k][0];
    float4 kb = *(const float4*)&qs[k][4];
    f32x2 k0 = (f32x2){ka.x, ka.y};
    f32x2 k1 = (f32x2){ka.z, ka.w};
    f32x2 k2 = (f32x2){kb.x, kb.y};
    f32x2 k3 = (f32x2){kb.z, kb.w};

    f32x2 d0 = pk_mul(k0, qp0[0]);
    d0 = pk_fma(k1, qp0[1], d0);
    d0 = pk_fma(k2, qp0[2], d0);
    d0 = pk_fma(k3, qp0[3], d0);
    f32x2 d1 = pk_mul(k0, qp1[0]);
    d1 = pk_fma(k1, qp1[1], d1);
    d1 = pk_fma(k2, qp1[2], d1);
    d1 = pk_fma(k3, qp1[3], d1);

    float e0 = EXPFN(d0.x + d0.y);
    float e1 = EXPFN(d1.x + d1.y);
    ps0 += e0; ps1 += e1;
    f32x2 ev0 = (f32x2){e0, e0};
    f32x2 ev1 = (f32x2){e1, e1};
    a0[0] = pk_fma(k0, ev0, a0[0]);
    a0[1] = pk_fma(k1, ev0, a0[1]);
    a0[2] = pk_fma(k2, ev0, a0[2]);
    a0[3] = pk_fma(k3, ev0, a0[3]);
    a1[0] = pk_fma(k0, ev1, a1[0]);
    a1[1] = pk_fma(k1, ev1, a1[1]);
    a1[2] = pk_fma(k2, ev1, a1[2]);
    a1[3] = pk_fma(k3, ev1, a1[3]);
  }

  size_t base = ((size_t)(bh * KSPLIT + ks)) * 9 * 1024;
#pragma unroll
  for (int j = 0; j < 4; j++) {
    apart[base + (2 * j) * 1024 + r0]     = a0[j].x;
    apart[base + (2 * j + 1) * 1024 + r0] = a0[j].y;
    apart[base + (2 * j) * 1024 + r1]     = a1[j].x;
    apart[base + (2 * j + 1) * 1024 + r1] = a1[j].y;
  }
  apart[base + 8 * 1024 + r0] = ps0;
  apart[base + 8 * 1024 + r1] = ps1;
}

// sum ksplit partials, normalize, write attn_out[b,s,64]
__global__ __launch_bounds__(256) void attn_combine(
    const float* __restrict__ apart, float* __restrict__ attn_out) {
  int gid = blockIdx.x * 256 + threadIdx.x;
  int bh = gid >> 10, row = gid & 1023;
  int b = bh >> 3, h = bh & 7;
  float v[9];
#pragma unroll
  for (int c = 0; c < 9; c++) v[c] = 0.f;
  for (int ks = 0; ks < KSPLIT; ks++) {
    size_t base = ((size_t)(bh * KSPLIT + ks)) * 9 * 1024 + row;
#pragma unroll
    for (int c = 0; c < 9; c++) v[c] += apart[base + c * 1024];
  }
  float inv = 1.0f / v[8];
  float* op = attn_out + ((size_t)(b * Ssz + row)) * Dd + h * 8;
  *(float4*)op       = make_float4(v[0] * inv, v[1] * inv, v[2] * inv, v[3] * inv);
  *(float4*)(op + 4) = make_float4(v[4] * inv, v[5] * inv, v[6] * inv, v[7] * inv);
}

// ------------------- tail1: combine-matvec + residual + LN1 (in-place on x)
// Wc row `lane` lives in 64 VGPRs; activation broadcast by v_readlane.
__global__ __launch_bounds__(256) void tail1_kernel(
    float* __restrict__ x, const float* __restrict__ attn,
    const float* __restrict__ Wc,
    const float* __restrict__ g1, const float* __restrict__ bb1) {
  int lane = threadIdx.x & 63, w = threadIdx.x >> 6;
  float wc[64];
#pragma unroll
  for (int i = 0; i < 16; i++) {
    float4 v = *(const float4*)&Wc[lane * 64 + i * 4];
    wc[4 * i] = v.x; wc[4 * i + 1] = v.y; wc[4 * i + 2] = v.z; wc[4 * i + 3] = v.w;
  }
  float g = g1[lane], bb = bb1[lane];
  int tok0 = blockIdx.x * 16 + w * 4;
  for (int it = 0; it < 4; ++it) {
    size_t base = (size_t)(tok0 + it) * Dd + lane;
    float xd = x[base];
    float av = attn[base];
    float y0 = 0.f, y1 = 0.f, y2 = 0.f, y3 = 0.f;
#pragma unroll
    for (int k = 0; k < 64; k += 4) {
      y0 = fmaf(rdlane(av, k),     wc[k],     y0);
      y1 = fmaf(rdlane(av, k + 1), wc[k + 1], y1);
      y2 = fmaf(rdlane(av, k + 2), wc[k + 2], y2);
      y3 = fmaf(rdlane(av, k + 3), wc[k + 3], y3);
    }
    float r = xd + ((y0 + y1) + (y2 + y3));
    float mu = wave_reduce_sum(r) * (1.f / 64.f);
    float t = r - mu;
    float var = wave_reduce_sum(t * t) * (1.f / 64.f);
    x[base] = t * rsqrtf(var + 1e-5f) * g + bb;
  }
}

// ------------------- tail2: quantum FFN + residual + LN2 (in-place), pooling
__global__ __launch_bounds__(256) void tail2_kernel(
    float* __restrict__ x,
    const float* __restrict__ g2, const float* __restrict__ bb2,
    const float* __restrict__ fth,
    const float* __restrict__ W1, const float* __restrict__ fb1,
    const float* __restrict__ W2, const float* __restrict__ fb2,
    float* __restrict__ partial, int do_partial) {
  __shared__ float red[4][64];
  int lane = threadIdx.x & 63, w = threadIdx.x >> 6;
  float w2[128];
#pragma unroll
  for (int i = 0; i < 32; i++) {
    float4 v = *(const float4*)&W2[lane * 128 + i * 4];
    w2[4 * i] = v.x; w2[4 * i + 1] = v.y; w2[4 * i + 2] = v.z; w2[4 * i + 3] = v.w;
  }
  float w1a[8], w1b[8];
#pragma unroll
  for (int i = 0; i < 8; i++) {
    w1a[i] = W1[lane * 8 + i];
    w1b[i] = W1[(lane + 64) * 8 + i];
  }
  float fb1a = fb1[lane], fb1b = fb1[lane + 64];
  float g = g2[lane], bb = bb2[lane];
  float fb2d = fb2[lane];
  float cth[8];
#pragma unroll
  for (int i = 0; i < 8; i++) cth[i] = __cosf(fth[i]);

  float pool = 0.f;
  int tok0 = blockIdx.x * 16 + w * 4;
  for (int it = 0; it < 4; ++it) {
    size_t base = (size_t)(tok0 + it) * Dd + lane;
    float x1 = x[base];
    float z[8];
#pragma unroll
    for (int i = 0; i < 8; i++) z[i] = __cosf(rdlane(x1, i)) * cth[i];
    float ha = fb1a, hb = fb1b;
#pragma unroll
    for (int i = 0; i < 8; i++) { ha = fmaf(z[i], w1a[i], ha); hb = fmaf(z[i], w1b[i], hb); }
    ha = fmaxf(ha, 0.f); hb = fmaxf(hb, 0.f);
    float f0 = 0.f, f1 = 0.f, f2 = 0.f, f3 = 0.f;
#pragma unroll
    for (int j = 0; j < 64; j += 4) {
      f0 = fmaf(rdlane(ha, j),     w2[j],     f0);
      f1 = fmaf(rdlane(ha, j + 1), w2[j + 1], f1);
      f2 = fmaf(rdlane(ha, j + 2), w2[j + 2], f2);
      f3 = fmaf(rdlane(ha, j + 3), w2[j + 3], f3);
    }
#pragma unroll
    for (int j = 0; j < 64; j += 4) {
      f0 = fmaf(rdlane(hb, j),     w2[64 + j],     f0);
      f1 = fmaf(rdlane(hb, j + 1), w2[64 + j + 1], f1);
      f2 = fmaf(rdlane(hb, j + 2), w2[64 + j + 2], f2);
      f3 = fmaf(rdlane(hb, j + 3), w2[64 + j + 3], f3);
    }
    float f = fb2d + ((f0 + f1) + (f2 + f3));
    float r2 = x1 + f;
    float mu2 = wave_reduce_sum(r2) * (1.f / 64.f);
    float t2 = r2 - mu2;
    float var2 = wave_reduce_sum(t2 * t2) * (1.f / 64.f);
    float xo = t2 * rsqrtf(var2 + 1e-5f) * g + bb;
    x[base] = xo;
    pool += xo;
  }
  if (do_partial) {
    red[w][lane] = pool;
    __syncthreads();
    if (w == 0) {
      float s = red[0][lane] + red[1][lane] + red[2][lane] + red[3][lane];
      partial[(size_t)blockIdx.x * 64 + lane] = s;
    }
  }
}

// ------------------------------------------------ pooled mean + MLP head
// grid = 16 (one block per batch row), 128 threads.
__global__ __launch_bounds__(128) void head_kernel(
    const float* __restrict__ partial,   // [1024][64]
    const float* eW1, const float* eb1, const float* eW2, const float* eb2,
    const float* eW3, const float* eb3, const float* dW1, const float* db1v,
    const float* dW2, const float* db2v, const float* dW3, const float* db3v,
    const float* cW, const float* cb, float* __restrict__ out) {
  __shared__ float bufP[64];
  __shared__ float bufA[128];
  __shared__ float bufB[128];
  int b = blockIdx.x, t = threadIdx.x;
  if (t < 64) {
    float s = 0.f;
    for (int c = 0; c < 64; ++c) s += partial[(size_t)(b * 64 + c) * 64 + t];
    bufP[t] = s * (1.f / 1024.f);
  }
  __syncthreads();
  {
    float v = eb1[t];
    for (int d = 0; d < 64; d++) v = fmaf(bufP[d], eW1[t * 64 + d], v);
    bufA[t] = fmaxf(v, 0.f);
  }
  __syncthreads();
  if (t < 64) {
    float v = eb2[t];
    for (int j = 0; j < 128; j++) v = fmaf(bufA[j], eW2[t * 128 + j], v);
    bufB[t] = fmaxf(v, 0.f);
  }
  __syncthreads();
  if (t < 32) {
    float v = eb3[t];
    for (int d = 0; d < 64; d++) v = fmaf(bufB[d], eW3[t * 64 + d], v);
    bufA[t] = v;   // latent in bufA[0..31]
  }
  __syncthreads();
  if (t < 64) {
    float v = db1v[t];
    for (int k = 0; k < 32; k++) v = fmaf(bufA[k], dW1[t * 32 + k], v);
    bufB[t] = fmaxf(v, 0.f);
  }
  __syncthreads();
  {
    float v = db2v[t];
    for (int k = 0; k < 64; k++) v = fmaf(bufB[k], dW2[t * 64 + k], v);
    bufA[t] = fmaxf(v, 0.f);
  }
  __syncthreads();
  if (t < 64) {
    float v = db3v[t];
    for (int j = 0; j < 128; j++) v = fmaf(bufA[j], dW3[t * 128 + j], v);
    bufB[t] = v;
  }
  __syncthreads();
  if (t < 10) {
    float v = cb[t];
    for (int d = 0; d < 64; d++) v = fmaf(bufB[d], cW[t * 64 + d], v);
    out[b * 10 + t] = v;
  }
}

extern "C" void kernel_launch(void* const* d_in, const int* in_sizes, int n_in,
                              void* d_out, int out_size, void* d_ws, size_t ws_size,
                              hipStream_t stream) {
  const int*   tokens     = (const int*)d_in[0];
  const float* emb        = (const float*)d_in[1];
  const float* attn_theta = (const float*)d_in[2];
  const float* combine_W  = (const float*)d_in[3];
  const float* ln1_g      = (const float*)d_in[4];
  const float* ln1_b      = (const float*)d_in[5];
  const float* ln2_g      = (const float*)d_in[6];
  const float* ln2_b      = (const float*)d_in[7];
  const float* ffn_theta  = (const float*)d_in[8];
  const float* ffn_W1     = (const float*)d_in[9];
  const float* ffn_b1     = (const float*)d_in[10];
  const float* ffn_W2     = (const float*)d_in[11];
  const float* ffn_b2     = (const float*)d_in[12];
  const float* enc_W1 = (const float*)d_in[13]; const float* enc_b1 = (const float*)d_in[14];
  const float* enc_W2 = (const float*)d_in[15]; const float* enc_b2 = (const float*)d_in[16];
  const float* enc_W3 = (const float*)d_in[17]; const float* enc_b3 = (const float*)d_in[18];
  const float* dec_W1 = (const float*)d_in[19]; const float* dec_b1 = (const float*)d_in[20];
  const float* dec_W2 = (const float*)d_in[21]; const float* dec_b2 = (const float*)d_in[22];
  const float* dec_W3 = (const float*)d_in[23]; const float* dec_b3 = (const float*)d_in[24];
  const float* cls_W  = (const float*)d_in[25]; const float* cls_b  = (const float*)d_in[26];

  float* x        = (float*)d_ws;
  float* attn_out = x + (size_t)TOKENS * 64;
  float* apart    = attn_out + (size_t)TOKENS * 64;
  float* partial  = apart + (size_t)128 * KSPLIT * 9 * 1024;
  float* out      = (float*)d_out;

  embed_kernel<<<(TOKENS * Dd + 255) / 256, 256, 0, stream>>>(tokens, emb, x);
  for (int l = 0; l < 2; ++l) {
    attn_kernel<<<128 * 2 * KSPLIT, 256, 0, stream>>>(x, attn_theta + l * 8, apart);
    attn_combine<<<128 * 1024 / 256, 256, 0, stream>>>(apart, attn_out);
    tail1_kernel<<<TOKENS / 16, 256, 0, stream>>>(
        x, attn_out, combine_W + l * 4096, ln1_g + l * 64, ln1_b + l * 64);
    tail2_kernel<<<TOKENS / 16, 256, 0, stream>>>(
        x, ln2_g + l * 64, ln2_b + l * 64,
        ffn_theta + l * 8, ffn_W1 + l * 1024, ffn_b1 + l * 128,
        ffn_W2 + l * 8192, ffn_b2 + l * 64, partial, (l == 1) ? 1 : 0);
  }
  head_kernel<<<16, 128, 0, stream>>>(partial, enc_W1, enc_b1, enc_W2, enc_b2,
                                      enc_W3, enc_b3, dec_W1, dec_b1, dec_W2,
                                      dec_b2, dec_W3, dec_b3, cls_W, cls_b, out);
}